// Round 10
// baseline (100.801 us; speedup 1.0000x reference)
//
#include <hip/hip_runtime.h>
#include <math.h>

#define BB 64
#define AA 8732
#define DD 85
#define GG 32
#define CC 81
#define TILE 64
#define NT 137        /* ceil(8732/64) tiles */
#define TPB 18        /* tiles per k_loss block */
#define NTB 8         /* k_loss grid.x ; 512 blocks = exactly 2/CU */
#define BLKANCH (TPB * TILE)   /* 1152 anchors per block */

// ---------------- workspace layout (bytes) ----------------
// all_neg:     0        .. 2235392   (B*A float)
// partials:    2235392  .. 2237440   (B*NTB float)
// batch_total: 2237440  .. 2237696   (B float)
// bestp:       2237696  .. 2245888   (B*G int32)
// n_pos:       2245888  .. 2246144   (B int32)   } zeroed by k_match g==0 blk
// done_sel:    2246144  .. 2246148   (int32)     }

typedef __attribute__((address_space(3))) unsigned int lds_u32;
typedef const __attribute__((address_space(1))) unsigned int glb_u32;

__device__ __forceinline__ float smoothl1(float d) {
  float ad = fabsf(d);
  return ad < 1.0f ? 0.5f * d * d : ad - 0.5f;
}

__device__ __forceinline__ float frcp(float x) {
  return __builtin_amdgcn_rcpf(x);
}

// Stage B only: per-(b,g) best anchor (forced match argmax). grid (GG, B).
__global__ __launch_bounds__(256) void k_match(
    const float* __restrict__ anchors, const float* __restrict__ gt_boxes,
    const int* __restrict__ gt_counts, int* __restrict__ bestp,
    int* __restrict__ n_pos, int* __restrict__ done_sel)
{
  const int g = blockIdx.x;
  const int b = blockIdx.y;
  if (g == 0 && threadIdx.x == 0) {
    n_pos[b] = 0;
    if (b == 0) *done_sel = 0;
  }
  const int count = gt_counts[b];
  if (g >= count) return;

  __shared__ float wv[4];
  __shared__ int wi[4];

  float4 gb = reinterpret_cast<const float4*>(gt_boxes)[b * GG + g];
  const float gx0s = gb.x - gb.z * 0.5f, gy0s = gb.y - gb.w * 0.5f;
  const float gx1s = gb.x + gb.z * 0.5f, gy1s = gb.y + gb.w * 0.5f;
  const float gars = (gx1s - gx0s) * (gy1s - gy0s);

  float bv = -2.0f; int bi = AA;
  for (int a = threadIdx.x; a < AA; a += 256) {
    float4 an = reinterpret_cast<const float4*>(anchors)[a];
    float ax0 = an.x - an.z * 0.5f, ay0 = an.y - an.w * 0.5f;
    float ax1 = an.x + an.z * 0.5f, ay1 = an.y + an.w * 0.5f;
    float aar = (ax1 - ax0) * (ay1 - ay0);
    float iw = fmaxf(fminf(gx1s, ax1) - fmaxf(gx0s, ax0), 0.0f);
    float ih = fmaxf(fminf(gy1s, ay1) - fmaxf(gy0s, ay0), 0.0f);
    float inter = iw * ih;
    float iou = inter * frcp(gars + aar - inter);
    if (iou > bv || (iou == bv && a < bi)) { bv = iou; bi = a; }
  }
  #pragma unroll
  for (int m = 1; m < 64; m <<= 1) {
    float ov = __shfl_xor(bv, m);
    int   oi = __shfl_xor(bi, m);
    if (ov > bv || (ov == bv && oi < bi)) { bv = ov; bi = oi; }
  }
  if ((threadIdx.x & 63) == 0) { wv[threadIdx.x >> 6] = bv; wi[threadIdx.x >> 6] = bi; }
  __syncthreads();
  if (threadIdx.x == 0) {
    float fv = wv[0]; int fi = wi[0];
    #pragma unroll
    for (int w = 1; w < 4; ++w)
      if (wv[w] > fv || (wv[w] == fv && wi[w] < fi)) { fv = wv[w]; fi = wi[w]; }
    bestp[b * GG + g] = fi;
  }
}

// Heavy pass v4: grid (NTB, B), 256 threads, 4 threads/row.
// Matching inlined (LDS GT boxes), anchors LDS-staged -> NO register-consumed
// VMEM in the compute phase. Fast blocks use a counted-vmcnt 2-deep pipeline
// (loads never drain to 0 in the loop); the ragged last block uses full drains.
__global__ __launch_bounds__(256) void k_loss(
    const float* __restrict__ pred, const float* __restrict__ anchors,
    const float* __restrict__ gt_boxes, const int* __restrict__ gt_labels,
    const int* __restrict__ gt_counts, const int* __restrict__ bestp,
    float* __restrict__ all_neg, float* __restrict__ partials,
    int* __restrict__ n_pos)
{
  const int b = blockIdx.y;
  const int t0 = blockIdx.x * TPB;
  const int t1 = min(t0 + TPB, NT);
  const int abase = t0 * TILE;
  const int nanch = min(BLKANCH, AA - abase);
  const int tid = threadIdx.x;
  const bool fast = (blockIdx.x < NTB - 1);   // last block is ragged

  __shared__ float bufs[2][TILE * DD];   // 43520 B
  __shared__ float4 anch[BLKANCH];       // 18432 B
  __shared__ int ovr[BLKANCH];           // 4608 B
  __shared__ float sgx0[GG], sgy0[GG], sgx1[GG], sgy1[GG], sgar[GG];
  __shared__ float4 sgb[GG];
  __shared__ int slab[GG];
  __shared__ float wsum[4];
  __shared__ int wcnt[4];

  const int cnt = gt_counts[b];

  // small loads + LDS init (drained by the cheap early __syncthreads)
  if (tid < GG) {
    float4 gb = reinterpret_cast<const float4*>(gt_boxes)[b * GG + tid];
    sgb[tid] = gb;
    float x0 = gb.x - gb.z * 0.5f, y0 = gb.y - gb.w * 0.5f;
    float x1 = gb.x + gb.z * 0.5f, y1 = gb.y + gb.w * 0.5f;
    sgx0[tid] = x0; sgy0[tid] = y0; sgx1[tid] = x1; sgy1[tid] = y1;
    sgar[tid] = (x1 - x0) * (y1 - y0);
    slab[tid] = gt_labels[b * GG + tid];
  }
  for (int i = tid; i < BLKANCH; i += 256) ovr[i] = -1;
  __syncthreads();
  // forced-match scatter (max g == ascending last-write-wins); tiny loads only
  if (tid < GG && tid < cnt) {
    int p = bestp[b * GG + tid];
    if (p >= abase && p < abase + nanch) atomicMax(&ovr[p - abase], tid);
  }

  #define PF_TILE(t, bufp)                                                   \
    do {                                                                     \
      const int a0_ = (t) * TILE;                                            \
      const int nch_ = (min(TILE, AA - a0_) * DD) >> 2;                      \
      const float* s_ = pred + ((size_t)b * AA + a0_) * DD;                  \
      _Pragma("unroll")                                                      \
      for (int j_ = 0; j_ < 6; ++j_) {                                       \
        int c_ = j_ * 256 + tid;                                             \
        if (c_ < nch_)                                                       \
          __builtin_amdgcn_global_load_lds(                                  \
              (glb_u32*)(s_ + c_ * 4), (lds_u32*)((bufp) + c_ * 4), 16, 0, 0);\
      }                                                                      \
    } while (0)

  #define PF_ANCH()                                                          \
    do {                                                                     \
      const float* s_ = anchors + (size_t)abase * 4;                         \
      float* d_ = (float*)&anch[0];                                          \
      _Pragma("unroll")                                                      \
      for (int j_ = 0; j_ < 5; ++j_) {                                       \
        int c_ = j_ * 256 + tid;                                             \
        if (c_ < nanch)                                                      \
          __builtin_amdgcn_global_load_lds(                                  \
              (glb_u32*)(s_ + c_ * 4), (lds_u32*)(d_ + c_ * 4), 16, 0, 0);   \
      }                                                                      \
    } while (0)

  const int r = tid >> 2;
  const int sub = tid & 3;
  float acc = 0.0f;
  int poscnt = 0;
  int cur = 0;

  // shared per-tile compute (all operands LDS/registers; only STOREs to global)
  auto compute_tile = [&](int t, int cur_) {
    const int a0 = t * TILE;
    const int nr = min(TILE, AA - a0);
    const float* rows = &bufs[cur_][0];
    if (r < nr) {
      const int a = a0 + r;
      const int ai = a - abase;
      float4 an = anch[ai];
      float ax0 = an.x - an.z * 0.5f, ay0 = an.y - an.w * 0.5f;
      float ax1 = an.x + an.z * 0.5f, ay1 = an.y + an.w * 0.5f;
      float aar = (ax1 - ax0) * (ay1 - ay0);

      // inline stage-A match: lane sub takes g = sub, sub+4, ...
      float bv = -1.0f; int bg = 0;
      for (int g = sub; g < cnt; g += 4) {
        float iw = fmaxf(fminf(sgx1[g], ax1) - fmaxf(sgx0[g], ax0), 0.0f);
        float ih = fmaxf(fminf(sgy1[g], ay1) - fmaxf(sgy0[g], ay0), 0.0f);
        float inter = iw * ih;
        float iou = inter * frcp(sgar[g] + aar - inter);
        if (iou > bv) { bv = iou; bg = g; }   // per-lane first-max (g asc)
      }
      #pragma unroll
      for (int msk = 1; msk <= 2; msk <<= 1) {
        float ov = __shfl_xor(bv, msk);
        int   og = __shfl_xor(bg, msk);
        if (ov > bv || (ov == bv && og < bg)) { bv = ov; bg = og; }
      }
      int m = (bv > 0.5f) ? bg : -1;
      { int o = ovr[ai]; if (o >= 0) m = o; }   // forced override wins

      const float* row = rows + r * DD + 4;
      float v[21];
      float mx = -INFINITY;
      #pragma unroll
      for (int k = 0; k < 21; ++k) {
        const int cc = 4 * k + sub;
        float x = (cc < CC) ? row[cc] : -INFINITY;
        v[k] = x;
        mx = fmaxf(mx, x);
      }
      #pragma unroll
      for (int msk = 1; msk <= 2; msk <<= 1)
        mx = fmaxf(mx, __shfl_xor(mx, msk));
      float s = 0.0f;
      #pragma unroll
      for (int k = 0; k < 21; ++k) s += __expf(v[k] - mx);
      #pragma unroll
      for (int msk = 1; msk <= 2; msk <<= 1) s += __shfl_xor(s, msk);
      const float lse = mx + __logf(s);

      if (sub == 0) {
        if (m >= 0) {
          poscnt += 1;
          const int tgt = slab[m] + 1;
          float cls_ce = lse - row[tgt];
          float4 gb = sgb[m];
          float tx = (gb.x - an.x) / an.z;
          float ty = (gb.y - an.y) / an.w;
          float tw = __logf(gb.z) - __logf(an.z);
          float th = __logf(gb.w) - __logf(an.w);
          acc += smoothl1(rows[r * DD + 0] - tx)
               + smoothl1(rows[r * DD + 1] - ty)
               + smoothl1(rows[r * DD + 2] - tw)
               + smoothl1(rows[r * DD + 3] - th)
               + cls_ce;
          all_neg[b * AA + a] = 0.0f;
        } else {
          float ce = lse - row[0];
          all_neg[b * AA + a] = fmaxf(ce, 0.0f);
        }
      }
    }
  };

  if (fast) {
    // counted-vmcnt 2-deep pipeline (all tiles full: nr==64, 6 issues/wave max)
    PF_ANCH();
    PF_TILE(t0, &bufs[0][0]);
    PF_TILE(t0 + 1, &bufs[1][0]);
    asm volatile("s_waitcnt vmcnt(5) lgkmcnt(0)" ::: "memory");
    __builtin_amdgcn_s_barrier();          // anchors + tile t0 resident

    for (int t = t0; t < t1; ++t) {
      compute_tile(t, cur);
      if (t + 1 < t1) {
        __builtin_amdgcn_s_barrier();      // all waves done reading bufs[cur]
        if (t + 2 < t1) {
          PF_TILE(t + 2, &bufs[cur][0]);
          asm volatile("s_waitcnt vmcnt(5) lgkmcnt(0)" ::: "memory");
        } else {
          asm volatile("s_waitcnt vmcnt(0) lgkmcnt(0)" ::: "memory");
        }
        __builtin_amdgcn_s_barrier();      // tile t+1 visible to all
        cur ^= 1;
      }
    }
  } else {
    // ragged last block: classic full-drain double buffer
    PF_ANCH();
    PF_TILE(t0, &bufs[0][0]);
    __syncthreads();
    for (int t = t0; t < t1; ++t) {
      if (t + 1 < t1) {
        PF_TILE(t + 1, &bufs[cur ^ 1][0]);
        __builtin_amdgcn_sched_barrier(0);
      }
      compute_tile(t, cur);
      __syncthreads();
      cur ^= 1;
    }
  }

  #pragma unroll
  for (int msk = 1; msk < 64; msk <<= 1) {
    acc    += __shfl_xor(acc, msk);
    poscnt += __shfl_xor(poscnt, msk);
  }
  if ((tid & 63) == 0) {
    wsum[tid >> 6] = acc;
    wcnt[tid >> 6] = poscnt;
  }
  __syncthreads();
  if (tid == 0) {
    partials[b * NTB + blockIdx.x] = (wsum[0] + wsum[1]) + (wsum[2] + wsum[3]);
    int c = wcnt[0] + wcnt[1] + wcnt[2] + wcnt[3];
    if (c) atomicAdd(&n_pos[b], c);        // integer add: order-independent
  }
  #undef PF_TILE
  #undef PF_ANCH
}

// ---- per-batch top-K sum via radix select; last block also writes out[0].
__global__ __launch_bounds__(1024) void k_select(
    const float* __restrict__ all_neg, const float* __restrict__ partials,
    const int* __restrict__ n_pos, float* __restrict__ batch_total,
    int* __restrict__ done_sel, float* __restrict__ out)
{
  const int b = blockIdx.x;
  const int tid = threadIdx.x;
  __shared__ unsigned u[AA];           // 34928 B
  __shared__ int hist16[16][257];      // per-wave histograms
  __shared__ int hist[256];
  __shared__ unsigned sh_pref;
  __shared__ int sh_k;
  __shared__ int sflag;
  __shared__ float wf[16];
  __shared__ int wc[16];

  {
    const float* srcg = all_neg + (size_t)b * AA;   // 16B-aligned
    #pragma unroll
    for (int j = 0; j < 3; ++j) {
      int c = j * 1024 + tid;
      if (c < 2183)
        __builtin_amdgcn_global_load_lds(
            (glb_u32*)(srcg + c * 4), (lds_u32*)((float*)u + c * 4), 16, 0, 0);
    }
  }

  // wave-parallel partials sum (overlaps staging)
  float ps = 0.0f;
  if (tid < NTB) {
    float pv = partials[b * NTB + tid];
    #pragma unroll
    for (int m = 1; m < NTB; m <<= 1) pv += __shfl_xor(pv, m);
    ps = pv;
  }
  __syncthreads();

  const int np = n_pos[b];
  const int K = min(3 * np, AA - 1);
  const int wvid = tid >> 6;

  unsigned prefix = 0;
  int kk = K;
  for (int shift = 24; shift >= 0; shift -= 8) {
    int* hflat = &hist16[0][0];
    for (int i = tid; i < 16 * 257; i += 1024) hflat[i] = 0;
    __syncthreads();
    const unsigned hmask = (shift == 24) ? 0u : (0xFFFFFFFFu << (shift + 8));
    for (int i = tid; i < AA; i += 1024) {
      unsigned x = u[i];
      if ((x & hmask) == prefix)
        atomicAdd(&hist16[wvid][(x >> shift) & 255], 1);
    }
    __syncthreads();
    if (tid < 256) {
      int s = 0;
      #pragma unroll
      for (int h = 0; h < 16; ++h) s += hist16[h][tid];
      hist[tid] = s;
    }
    __syncthreads();
    // barrier-free suffix scan + bin pick: wave 0 only
    if (tid < 64) {
      int h0 = hist[4 * tid], h1 = hist[4 * tid + 1];
      int h2 = hist[4 * tid + 2], h3 = hist[4 * tid + 3];
      int lsum = h0 + h1 + h2 + h3;
      int suf = lsum;
      #pragma unroll
      for (int off = 1; off < 64; off <<= 1) {
        int o = __shfl_down(suf, off);
        suf += (tid + off < 64) ? o : 0;
      }
      int after = suf - lsum;
      int s3 = h3 + after, s2 = h2 + s3, s1 = h1 + s2, s0 = h0 + s1;
      if (s0 >= kk && s1 < kk)    { sh_pref = prefix | ((unsigned)(4*tid+0) << shift); sh_k = kk - s1; }
      if (s1 >= kk && s2 < kk)    { sh_pref = prefix | ((unsigned)(4*tid+1) << shift); sh_k = kk - s2; }
      if (s2 >= kk && s3 < kk)    { sh_pref = prefix | ((unsigned)(4*tid+2) << shift); sh_k = kk - s3; }
      if (s3 >= kk && after < kk) { sh_pref = prefix | ((unsigned)(4*tid+3) << shift); sh_k = kk - after; }
    }
    __syncthreads();
    prefix = sh_pref;
    kk = sh_k;
    __syncthreads();
  }
  const float tstar = __uint_as_float(prefix);   // exact K-th largest

  float ssum = 0.0f; int cgt = 0;
  for (int i = tid; i < AA; i += 1024) {
    float x = __uint_as_float(u[i]);
    if (x > tstar) { ssum += x; cgt += 1; }
  }
  #pragma unroll
  for (int m = 1; m < 64; m <<= 1) {
    ssum += __shfl_xor(ssum, m);
    cgt  += __shfl_xor(cgt, m);
  }
  if ((tid & 63) == 0) { wf[wvid] = ssum; wc[wvid] = cgt; }
  __syncthreads();
  if (tid == 0) {
    float S = 0.0f; int Cg = 0;
    #pragma unroll
    for (int w = 0; w < 16; ++w) { S += wf[w]; Cg += wc[w]; }
    float neg_sum = S + (float)(K - Cg) * tstar;
    batch_total[b] = (ps + neg_sum) / (float)np;
    __threadfence();                       // release (4B dirty: cheap)
    int old = atomicAdd(done_sel, 1);
    sflag = (old == BB - 1) ? 1 : 0;
  }
  __syncthreads();

  if (sflag) {                             // last finishing block: final sum
    __threadfence();                       // acquire
    if (tid < 64) {
      float v = batch_total[tid];
      #pragma unroll
      for (int m = 1; m < 64; m <<= 1) v += __shfl_xor(v, m);
      if (tid == 0) out[0] = v;
    }
  }
}

extern "C" void kernel_launch(void* const* d_in, const int* in_sizes, int n_in,
                              void* d_out, int out_size, void* d_ws, size_t ws_size,
                              hipStream_t stream) {
  (void)in_sizes; (void)n_in; (void)out_size; (void)ws_size;
  const float* pred      = (const float*)d_in[0];
  const float* anchors   = (const float*)d_in[1];
  const float* gt_boxes  = (const float*)d_in[2];
  const int*   gt_labels = (const int*)d_in[3];
  const int*   gt_counts = (const int*)d_in[4];

  char* ws = (char*)d_ws;
  float* all_neg     = (float*)(ws + 0);
  float* partials    = (float*)(ws + 2235392);
  float* batch_total = (float*)(ws + 2237440);
  int*   bestp       = (int*)(ws + 2237696);
  int*   n_pos       = (int*)(ws + 2245888);
  int*   done_sel    = (int*)(ws + 2246144);
  float* out = (float*)d_out;

  hipLaunchKernelGGL(k_match, dim3(GG, BB), dim3(256), 0, stream,
                     anchors, gt_boxes, gt_counts, bestp, n_pos, done_sel);
  hipLaunchKernelGGL(k_loss, dim3(NTB, BB), dim3(256), 0, stream,
                     pred, anchors, gt_boxes, gt_labels, gt_counts, bestp,
                     all_neg, partials, n_pos);
  hipLaunchKernelGGL(k_select, dim3(BB), dim3(1024), 0, stream,
                     all_neg, partials, n_pos, batch_total, done_sel, out);
}

// Round 11
// 84.517 us; speedup vs baseline: 1.1927x; 1.1927x over previous
//
#include <hip/hip_runtime.h>
#include <math.h>

#define BB 64
#define AA 8732
#define DD 85
#define GG 32
#define CC 81
#define TILE 64
#define RPB 8         /* 64-row groups per k_loss block */
#define NTB 18        /* ceil(137/8) -> grid.x ; 1152 blocks */
#define NAB 35        /* ceil(8732/256) stage-A blocks in k_match */

// ---------------- workspace layout (bytes) ----------------
// match:       0        .. 2235392   (B*A int32)
// all_neg:     2235392  .. 4470784   (B*A float)
// partials:    4470784  .. 4475392   (B*NTB float)
// batch_total: 4475392  .. 4475648   (B float)
// bestp:       4475648  .. 4483840   (B*G int32)
// n_pos:       4483840  .. 4484096   (B int32)   } zeroed by k_match blk(0,b)
// done_sel:    4484096  .. 4484100   (int32)     }

typedef __attribute__((address_space(3))) unsigned int lds_u32;
typedef const __attribute__((address_space(1))) unsigned int glb_u32;

__device__ __forceinline__ float smoothl1(float d) {
  float ad = fabsf(d);
  return ad < 1.0f ? 0.5f * d * d : ad - 0.5f;
}

__device__ __forceinline__ float frcp(float x) {
  return __builtin_amdgcn_rcpf(x);
}

// Fused matcher (R9). grid (NAB+GG, B), 256 threads.
__global__ __launch_bounds__(256) void k_match(
    const float* __restrict__ anchors, const float* __restrict__ gt_boxes,
    const int* __restrict__ gt_counts, int* __restrict__ match,
    int* __restrict__ bestp, int* __restrict__ n_pos, int* __restrict__ done_sel)
{
  const int b = blockIdx.y;
  const int count = gt_counts[b];
  __shared__ float gx0[GG], gy0[GG], gx1[GG], gy1[GG], gar[GG];
  __shared__ float wv[4];
  __shared__ int wi[4];

  if (blockIdx.x < NAB) {
    if (blockIdx.x == 0 && threadIdx.x == 0) {
      n_pos[b] = 0;
      if (b == 0) *done_sel = 0;
    }
    if (threadIdx.x < GG) {
      float4 gb = reinterpret_cast<const float4*>(gt_boxes)[b * GG + threadIdx.x];
      float x0 = gb.x - gb.z * 0.5f, y0 = gb.y - gb.w * 0.5f;
      float x1 = gb.x + gb.z * 0.5f, y1 = gb.y + gb.w * 0.5f;
      gx0[threadIdx.x] = x0; gy0[threadIdx.x] = y0;
      gx1[threadIdx.x] = x1; gy1[threadIdx.x] = y1;
      gar[threadIdx.x] = (x1 - x0) * (y1 - y0);
    }
    __syncthreads();
    const int a = blockIdx.x * 256 + threadIdx.x;
    if (a < AA) {
      float4 an = reinterpret_cast<const float4*>(anchors)[a];
      float ax0 = an.x - an.z * 0.5f, ay0 = an.y - an.w * 0.5f;
      float ax1 = an.x + an.z * 0.5f, ay1 = an.y + an.w * 0.5f;
      float aar = (ax1 - ax0) * (ay1 - ay0);
      float best = -1.0f; int bi = 0;
      for (int g = 0; g < count; ++g) {
        float iw = fmaxf(fminf(gx1[g], ax1) - fmaxf(gx0[g], ax0), 0.0f);
        float ih = fmaxf(fminf(gy1[g], ay1) - fmaxf(gy0[g], ay0), 0.0f);
        float inter = iw * ih;
        float iou = inter * frcp(gar[g] + aar - inter);
        if (iou > best) { best = iou; bi = g; }   // first max wins
      }
      match[b * AA + a] = (best > 0.5f) ? bi : -1;
    }
  } else {
    const int g = blockIdx.x - NAB;
    if (g < count) {
      float4 gb = reinterpret_cast<const float4*>(gt_boxes)[b * GG + g];
      const float gx0s = gb.x - gb.z * 0.5f, gy0s = gb.y - gb.w * 0.5f;
      const float gx1s = gb.x + gb.z * 0.5f, gy1s = gb.y + gb.w * 0.5f;
      const float gars = (gx1s - gx0s) * (gy1s - gy0s);

      float bv = -2.0f; int bi = AA;
      for (int a = threadIdx.x; a < AA; a += 256) {
        float4 an = reinterpret_cast<const float4*>(anchors)[a];
        float ax0 = an.x - an.z * 0.5f, ay0 = an.y - an.w * 0.5f;
        float ax1 = an.x + an.z * 0.5f, ay1 = an.y + an.w * 0.5f;
        float aar = (ax1 - ax0) * (ay1 - ay0);
        float iw = fmaxf(fminf(gx1s, ax1) - fmaxf(gx0s, ax0), 0.0f);
        float ih = fmaxf(fminf(gy1s, ay1) - fmaxf(gy0s, ay0), 0.0f);
        float inter = iw * ih;
        float iou = inter * frcp(gars + aar - inter);
        if (iou > bv || (iou == bv && a < bi)) { bv = iou; bi = a; }
      }
      #pragma unroll
      for (int m = 1; m < 64; m <<= 1) {
        float ov = __shfl_xor(bv, m);
        int   oi = __shfl_xor(bi, m);
        if (ov > bv || (ov == bv && oi < bi)) { bv = ov; bi = oi; }
      }
      if ((threadIdx.x & 63) == 0) { wv[threadIdx.x >> 6] = bv; wi[threadIdx.x >> 6] = bi; }
      __syncthreads();
      if (threadIdx.x == 0) {
        float fv = wv[0]; int fi = wi[0];
        #pragma unroll
        for (int w = 1; w < 4; ++w)
          if (wv[w] > fv || (wv[w] == fv && wi[w] < fi)) { fv = wv[w]; fi = wi[w]; }
        bestp[b * GG + g] = fi;
      }
    }
  }
}

// Heavy pass v5: PURE STREAMING. grid (NTB, B), 256 threads, 4 threads/row.
// No LDS tiles, no per-tile barriers: each quad register-loads its own row
// (contiguous 340B, coalesced; row end via single-dword load -> no overread).
// Latency hidden by TLP (~16 waves/CU, ~5KB loads in flight per wave).
__global__ __launch_bounds__(256) void k_loss(
    const float* __restrict__ pred, const float* __restrict__ anchors,
    const float* __restrict__ gt_boxes, const int* __restrict__ gt_labels,
    const int* __restrict__ gt_counts, const int* __restrict__ match,
    const int* __restrict__ bestp, float* __restrict__ all_neg,
    float* __restrict__ partials, int* __restrict__ n_pos)
{
  const int b = blockIdx.y;
  const int abase = blockIdx.x * RPB * TILE;   // 512 anchors per block
  const int tid = threadIdx.x;
  __shared__ int ovr[RPB * TILE];              // 2048 B
  __shared__ float4 sgb[GG];
  __shared__ int slab[GG];
  __shared__ float wsum[4];
  __shared__ int wcnt[4];

  const int cnt = gt_counts[b];
  if (tid < GG) {
    sgb[tid] = reinterpret_cast<const float4*>(gt_boxes)[b * GG + tid];
    slab[tid] = gt_labels[b * GG + tid];
  }
  ovr[tid] = -1; ovr[tid + 256] = -1;
  __syncthreads();
  if (tid < GG && tid < cnt) {
    int p = bestp[b * GG + tid];
    int rel = p - abase;
    if (rel >= 0 && rel < RPB * TILE) atomicMax(&ovr[rel], tid);  // max g = last-write-wins
  }
  __syncthreads();   // the ONLY barriers in this kernel (prologue)

  const int r = tid >> 2;
  const int sub = tid & 3;
  float acc = 0.0f;
  int poscnt = 0;

  for (int i = 0; i < RPB; ++i) {
    const int a0 = abase + i * TILE;
    if (a0 >= AA) break;
    const int a = a0 + r;
    if (a < AA) {   // whole quad shares r -> uniform within the 4-lane group
      const float* base = pred + ((size_t)b * AA + a) * DD;
      // quad covers the row contiguously: chunk c = sub + 4j
      float4 s0 = *(const float4*)(base + (sub)      * 4);
      float4 s1 = *(const float4*)(base + (sub + 4)  * 4);
      float4 s2 = *(const float4*)(base + (sub + 8)  * 4);
      float4 s3 = *(const float4*)(base + (sub + 12) * 4);
      float4 s4 = *(const float4*)(base + (sub + 16) * 4);
      float4 s5f = make_float4(0.f, 0.f, 0.f, 0.f);
      float  s5x = 0.0f;
      if (sub == 0) s5f = *(const float4*)(base + 80);  // chunk 20: cc 76..79
      if (sub == 1) s5x = base[84];                     // cc 80 (exact, no overread)

      int m = match[b * AA + a];
      { int o = ovr[a - abase]; if (o >= 0) m = o; }
      const int tgt = (m >= 0) ? slab[m] + 1 : 0;

      // conf scan: chunk c holds cc = 4c-4 .. 4c-1 ; cb = cc-base for j=0
      const int cb = 4 * sub - 4;
      float mx = -INFINITY, xt = -INFINITY;
      #define SCAN(v, ccb)                                                   \
        { mx = fmaxf(fmaxf(fmaxf(mx, (v).x), (v).y), fmaxf((v).z, (v).w));   \
          if ((ccb) + 0 == tgt) xt = (v).x;                                  \
          if ((ccb) + 1 == tgt) xt = (v).y;                                  \
          if ((ccb) + 2 == tgt) xt = (v).z;                                  \
          if ((ccb) + 3 == tgt) xt = (v).w; }
      if (sub > 0) SCAN(s0, cb);            // sub0 chunk0 is loc, not conf
      SCAN(s1, cb + 16); SCAN(s2, cb + 32); SCAN(s3, cb + 48); SCAN(s4, cb + 64);
      if (sub == 0) SCAN(s5f, 76);
      if (sub == 1) { mx = fmaxf(mx, s5x); if (tgt == 80) xt = s5x; }
      #undef SCAN
      #pragma unroll
      for (int msk = 1; msk <= 2; msk <<= 1)
        mx = fmaxf(mx, __shfl_xor(mx, msk));

      float s = 0.0f;
      #define ESUM(v) s += __expf((v).x - mx) + __expf((v).y - mx) +          \
                           __expf((v).z - mx) + __expf((v).w - mx);
      if (sub > 0) ESUM(s0);
      ESUM(s1); ESUM(s2); ESUM(s3); ESUM(s4);
      if (sub == 0) ESUM(s5f);
      if (sub == 1) s += __expf(s5x - mx);
      #undef ESUM
      #pragma unroll
      for (int msk = 1; msk <= 2; msk <<= 1) {
        s  += __shfl_xor(s, msk);
        xt  = fmaxf(xt, __shfl_xor(xt, msk));
      }
      const float lse = mx + __logf(s);
      const float ce = lse - xt;            // tgt==0 for negatives -> same formula

      if (sub == 0) {
        if (m >= 0) {
          poscnt += 1;
          float4 an = reinterpret_cast<const float4*>(anchors)[a];
          float4 gb = sgb[m];
          float tx = (gb.x - an.x) / an.z;
          float ty = (gb.y - an.y) / an.w;
          float tw = __logf(gb.z) - __logf(an.z);
          float th = __logf(gb.w) - __logf(an.w);
          acc += smoothl1(s0.x - tx) + smoothl1(s0.y - ty)
               + smoothl1(s0.z - tw) + smoothl1(s0.w - th) + ce;
          all_neg[b * AA + a] = 0.0f;
        } else {
          all_neg[b * AA + a] = fmaxf(ce, 0.0f);
        }
      }
    }
  }

  #pragma unroll
  for (int msk = 1; msk < 64; msk <<= 1) {
    acc    += __shfl_xor(acc, msk);
    poscnt += __shfl_xor(poscnt, msk);
  }
  if ((tid & 63) == 0) {
    wsum[tid >> 6] = acc;
    wcnt[tid >> 6] = poscnt;
  }
  __syncthreads();
  if (tid == 0) {
    partials[b * NTB + blockIdx.x] = (wsum[0] + wsum[1]) + (wsum[2] + wsum[3]);
    int c = wcnt[0] + wcnt[1] + wcnt[2] + wcnt[3];
    if (c) atomicAdd(&n_pos[b], c);        // integer add: order-independent
  }
}

// ---- per-batch top-K sum via radix select; last block also writes out[0].
__global__ __launch_bounds__(1024) void k_select(
    const float* __restrict__ all_neg, const float* __restrict__ partials,
    const int* __restrict__ n_pos, float* __restrict__ batch_total,
    int* __restrict__ done_sel, float* __restrict__ out)
{
  const int b = blockIdx.x;
  const int tid = threadIdx.x;
  __shared__ unsigned u[AA];           // 34928 B
  __shared__ int hist16[16][257];      // per-wave histograms
  __shared__ int hist[256];
  __shared__ unsigned sh_pref;
  __shared__ int sh_k;
  __shared__ int sflag;
  __shared__ float wf[16];
  __shared__ int wc[16];

  {
    const float* srcg = all_neg + (size_t)b * AA;   // 16B-aligned
    #pragma unroll
    for (int j = 0; j < 3; ++j) {
      int c = j * 1024 + tid;
      if (c < 2183)
        __builtin_amdgcn_global_load_lds(
            (glb_u32*)(srcg + c * 4), (lds_u32*)((float*)u + c * 4), 16, 0, 0);
    }
  }

  // wave-parallel partials sum (overlaps staging); NTB=18 spans 32 lanes
  float ps = 0.0f;
  if (tid < 64) {
    float pv = (tid < NTB) ? partials[b * NTB + tid] : 0.0f;
    #pragma unroll
    for (int m = 1; m < 32; m <<= 1) pv += __shfl_xor(pv, m);
    ps = pv;
  }
  __syncthreads();

  const int np = n_pos[b];
  const int K = min(3 * np, AA - 1);
  const int wvid = tid >> 6;

  unsigned prefix = 0;
  int kk = K;
  for (int shift = 24; shift >= 0; shift -= 8) {
    int* hflat = &hist16[0][0];
    for (int i = tid; i < 16 * 257; i += 1024) hflat[i] = 0;
    __syncthreads();
    const unsigned hmask = (shift == 24) ? 0u : (0xFFFFFFFFu << (shift + 8));
    for (int i = tid; i < AA; i += 1024) {
      unsigned x = u[i];
      if ((x & hmask) == prefix)
        atomicAdd(&hist16[wvid][(x >> shift) & 255], 1);
    }
    __syncthreads();
    if (tid < 256) {
      int s = 0;
      #pragma unroll
      for (int h = 0; h < 16; ++h) s += hist16[h][tid];
      hist[tid] = s;
    }
    __syncthreads();
    // barrier-free suffix scan + bin pick: wave 0 only
    if (tid < 64) {
      int h0 = hist[4 * tid], h1 = hist[4 * tid + 1];
      int h2 = hist[4 * tid + 2], h3 = hist[4 * tid + 3];
      int lsum = h0 + h1 + h2 + h3;
      int suf = lsum;
      #pragma unroll
      for (int off = 1; off < 64; off <<= 1) {
        int o = __shfl_down(suf, off);
        suf += (tid + off < 64) ? o : 0;
      }
      int after = suf - lsum;
      int s3 = h3 + after, s2 = h2 + s3, s1 = h1 + s2, s0 = h0 + s1;
      if (s0 >= kk && s1 < kk)    { sh_pref = prefix | ((unsigned)(4*tid+0) << shift); sh_k = kk - s1; }
      if (s1 >= kk && s2 < kk)    { sh_pref = prefix | ((unsigned)(4*tid+1) << shift); sh_k = kk - s2; }
      if (s2 >= kk && s3 < kk)    { sh_pref = prefix | ((unsigned)(4*tid+2) << shift); sh_k = kk - s3; }
      if (s3 >= kk && after < kk) { sh_pref = prefix | ((unsigned)(4*tid+3) << shift); sh_k = kk - after; }
    }
    __syncthreads();
    prefix = sh_pref;
    kk = sh_k;
    __syncthreads();
  }
  const float tstar = __uint_as_float(prefix);   // exact K-th largest

  float ssum = 0.0f; int cgt = 0;
  for (int i = tid; i < AA; i += 1024) {
    float x = __uint_as_float(u[i]);
    if (x > tstar) { ssum += x; cgt += 1; }
  }
  #pragma unroll
  for (int m = 1; m < 64; m <<= 1) {
    ssum += __shfl_xor(ssum, m);
    cgt  += __shfl_xor(cgt, m);
  }
  if ((tid & 63) == 0) { wf[wvid] = ssum; wc[wvid] = cgt; }
  __syncthreads();
  if (tid == 0) {
    float S = 0.0f; int Cg = 0;
    #pragma unroll
    for (int w = 0; w < 16; ++w) { S += wf[w]; Cg += wc[w]; }
    float neg_sum = S + (float)(K - Cg) * tstar;
    batch_total[b] = (ps + neg_sum) / (float)np;
    __threadfence();                       // release (4B dirty: cheap)
    int old = atomicAdd(done_sel, 1);
    sflag = (old == BB - 1) ? 1 : 0;
  }
  __syncthreads();

  if (sflag) {                             // last finishing block: final sum
    __threadfence();                       // acquire
    if (tid < 64) {
      float v = batch_total[tid];
      #pragma unroll
      for (int m = 1; m < 64; m <<= 1) v += __shfl_xor(v, m);
      if (tid == 0) out[0] = v;
    }
  }
}

extern "C" void kernel_launch(void* const* d_in, const int* in_sizes, int n_in,
                              void* d_out, int out_size, void* d_ws, size_t ws_size,
                              hipStream_t stream) {
  (void)in_sizes; (void)n_in; (void)out_size; (void)ws_size;
  const float* pred      = (const float*)d_in[0];
  const float* anchors   = (const float*)d_in[1];
  const float* gt_boxes  = (const float*)d_in[2];
  const int*   gt_labels = (const int*)d_in[3];
  const int*   gt_counts = (const int*)d_in[4];

  char* ws = (char*)d_ws;
  int*   match       = (int*)(ws + 0);
  float* all_neg     = (float*)(ws + 2235392);
  float* partials    = (float*)(ws + 4470784);
  float* batch_total = (float*)(ws + 4475392);
  int*   bestp       = (int*)(ws + 4475648);
  int*   n_pos       = (int*)(ws + 4483840);
  int*   done_sel    = (int*)(ws + 4484096);
  float* out = (float*)d_out;

  hipLaunchKernelGGL(k_match, dim3(NAB + GG, BB), dim3(256), 0, stream,
                     anchors, gt_boxes, gt_counts, match, bestp, n_pos, done_sel);
  hipLaunchKernelGGL(k_loss, dim3(NTB, BB), dim3(256), 0, stream,
                     pred, anchors, gt_boxes, gt_labels, gt_counts, match, bestp,
                     all_neg, partials, n_pos);
  hipLaunchKernelGGL(k_select, dim3(BB), dim3(1024), 0, stream,
                     all_neg, partials, n_pos, batch_total, done_sel, out);
}